// Round 1
// baseline (5032.056 us; speedup 1.0000x reference)
//
#include <hip/hip_runtime.h>
#include <cstdint>

// ---------------------------------------------------------------------------
// RNNres: emb -> LSTM(T=2048,B=64,NHID=256) -> ragged mean pool -> ResNet head
// Strategy:
//   k0: convert emb_w / W_ih to f16, bias = b_ih + b_hh
//   k1: MFMA f16 GEMM: gate_table[v] = W_ih * emb_w[v] + bias   (50257 x 1024)
//   k2: persistent recurrence, 1 WG per batch element, W_hh resident in
//       VGPRs (92/128 half2 pairs/row) + LDS (36/128), v_dot2_f32_f16 MACs,
//       v_readlane h-broadcast, table-gather prefetch; pooling fused.
//   k3: tiny fp32 head (res block + classifier + log_softmax)
// ---------------------------------------------------------------------------

#define NTOKEN 50257
#define NINP 256
#define NHID 256
#define BB 64
#define TT 2048
#define NRES 10
#define NFC1 85
#define EPSV 1e-5f

typedef _Float16 f16;
typedef _Float16 f16x2 __attribute__((ext_vector_type(2)));
typedef _Float16 f16x8 __attribute__((ext_vector_type(8)));
typedef float f32x4 __attribute__((ext_vector_type(4)));

static __device__ __forceinline__ float sigm(float x) { return 1.0f / (1.0f + __expf(-x)); }
static __device__ __forceinline__ float tanh_(float x) {
  float ax = fabsf(x);
  float e = __expf(-2.0f * ax);
  float t = (1.0f - e) / (1.0f + e);
  return x < 0.0f ? -t : t;
}

static __device__ __forceinline__ float fdot2(f16x2 a, f16x2 b, float c) {
#if __has_builtin(__builtin_amdgcn_fdot2)
  return __builtin_amdgcn_fdot2(a, b, c, false);
#else
  return c + (float)a[0] * (float)b[0] + (float)a[1] * (float)b[1];
#endif
}

// ---------------------------------------------------------------- k0: convert
__global__ void k0_convert(const float* __restrict__ emb_w, const float* __restrict__ W_ih,
                           const float* __restrict__ b_ih, const float* __restrict__ b_hh,
                           f16* __restrict__ emb16, f16* __restrict__ wih16,
                           float* __restrict__ bias) {
  int64_t i = (int64_t)blockIdx.x * blockDim.x + threadIdx.x;
  if (i < (int64_t)NTOKEN * NINP) emb16[i] = (f16)emb_w[i];
  if (i < 4 * NHID * NINP) wih16[i] = (f16)W_ih[i];
  if (i < 4 * NHID) bias[i] = b_ih[i] + b_hh[i];
}

// ------------------------------------------------- k1: gate-table f16 GEMM
// C[v][n] = sum_k emb16[v][k] * wih16[n][k] + bias[n], stored f16.
// WG: 256 thr / 4 waves, C-tile 64(M) x 256(N), K staged in 32-blocks.
__global__ __launch_bounds__(256) void k1_gemm(const f16* __restrict__ emb16,
                                               const f16* __restrict__ wih16,
                                               const float* __restrict__ bias,
                                               f16* __restrict__ xgtab) {
  __shared__ __align__(16) f16 a_lds[64][40];   // pad 32->40 f16 (80B, 16B-aligned)
  __shared__ __align__(16) f16 b_lds[256][40];
  const int mt = blockIdx.x;
  const int nt0 = blockIdx.y * 256;
  const int tid = threadIdx.x;
  const int lane = tid & 63;
  const int w = tid >> 6;
  const int quad = lane >> 4;
  const int l16 = lane & 15;

  f32x4 acc[16];
#pragma unroll
  for (int i = 0; i < 16; i++) acc[i] = (f32x4){0.f, 0.f, 0.f, 0.f};

  const int ar = tid >> 2;
  int av = mt * 64 + ar;
  if (av > NTOKEN - 1) av = NTOKEN - 1;   // tail clamp (stores guarded below)
  const int ac = (tid & 3) * 8;

  for (int kb = 0; kb < 256; kb += 32) {
    // stage A: 64 vocab rows x 32 k (16B per thread)
    *(uint4*)&a_lds[ar][ac] = *(const uint4*)&emb16[av * 256 + kb + ac];
    // stage B: 256 n-rows x 32 k (64B per thread)
    {
      const uint4* bs = (const uint4*)&wih16[(nt0 + tid) * 256 + kb];
      uint4* bd = (uint4*)&b_lds[tid][0];
      bd[0] = bs[0]; bd[1] = bs[1]; bd[2] = bs[2]; bd[3] = bs[3];
    }
    __syncthreads();
    // A frag: A[m=lane&15][k=quad*8+j]
    f16x8 af = *(const f16x8*)&a_lds[w * 16 + l16][quad * 8];
#pragma unroll
    for (int nt = 0; nt < 16; nt++) {
      f16x8 bf = *(const f16x8*)&b_lds[nt * 16 + l16][quad * 8];  // B[k][n=lane&15]
      acc[nt] = __builtin_amdgcn_mfma_f32_16x16x32_f16(af, bf, acc[nt], 0, 0, 0);
    }
    __syncthreads();
  }
  // C/D: col = lane&15, row = quad*4 + reg
#pragma unroll
  for (int nt = 0; nt < 16; nt++) {
#pragma unroll
    for (int rg = 0; rg < 4; rg++) {
      int v = mt * 64 + w * 16 + quad * 4 + rg;
      if (v < NTOKEN) {
        int n = nt0 + nt * 16 + l16;
        xgtab[v * 1024 + n] = (f16)(acc[nt][rg] + bias[n]);
      }
    }
  }
}

// ------------------------------------------------------- k2: LSTM recurrence
// One WG per batch element. 512 threads; thread t owns gate rows t and t+512
// (t<256: i,g ; t>=256: f,o). W_hh packed half2: 92 pairs in VGPRs, 36 in LDS
// (transposed lw[m'][row] -> conflict-free). h broadcast via v_readlane.
#define RK 92
#define LK 36
__global__ __launch_bounds__(512) void k2_rnn(
    const int* __restrict__ input, const float* __restrict__ hx0,
    const float* __restrict__ cx0, const int* __restrict__ seq_len,
    const float* __restrict__ Whh, const f16* __restrict__ xgtab,
    float* __restrict__ feat, float* __restrict__ out_hx, float* __restrict__ out_cx) {
  __shared__ unsigned int lw[LK * 1024];          // 147456 B
  __shared__ __align__(16) float hbuf[NHID];
  __shared__ float fo_f[NHID];
  __shared__ float fo_o[NHID];

  const int b = blockIdx.x;
  const int tid = threadIdx.x;
  const int lane = tid & 63;
  const int r0 = tid, r1 = tid + 512;

  // ---- load + pack W_hh (fp32 -> half2), split regs/LDS
  unsigned int w0[RK], w1[RK];
#pragma unroll
  for (int m = 0; m < 128; m++) {
    float2 a = *(const float2*)&Whh[r0 * 256 + 2 * m];
    float2 d = *(const float2*)&Whh[r1 * 256 + 2 * m];
    f16x2 pa; pa[0] = (f16)a.x; pa[1] = (f16)a.y;
    f16x2 pd; pd[0] = (f16)d.x; pd[1] = (f16)d.y;
    unsigned int ua = __builtin_bit_cast(unsigned int, pa);
    unsigned int ud = __builtin_bit_cast(unsigned int, pd);
    if (m < RK) { w0[m] = ua; w1[m] = ud; }
    else { lw[(m - RK) * 1024 + r0] = ua; lw[(m - RK) * 1024 + r1] = ud; }
  }

  float c = 0.0f, pool = 0.0f, hnew = 0.0f;
  if (tid < NHID) {
    hbuf[tid] = hx0[b * NHID + tid];
    c = cx0[b * NHID + tid];
  }
  const int L = seq_len[b];
  __syncthreads();

  // pack h into per-lane half2: lane holds pairs (2*lane,2*lane+1) and +128
  unsigned int h2a, h2b;
  {
    float2 p = *(const float2*)&hbuf[2 * lane];
    float2 q = *(const float2*)&hbuf[128 + 2 * lane];
    f16x2 ph; ph[0] = (f16)p.x; ph[1] = (f16)p.y;
    f16x2 qh; qh[0] = (f16)q.x; qh[1] = (f16)q.y;
    h2a = __builtin_bit_cast(unsigned int, ph);
    h2b = __builtin_bit_cast(unsigned int, qh);
  }

  const int* tokp = input + b * TT;
  int tok_next = tokp[1];
  // first step's x-gates (one-time stall is fine)
  float xga, xgb;
  {
    int tok0 = tokp[0];
    xga = (float)xgtab[tok0 * 1024 + r0];
    xgb = (float)xgtab[tok0 * 1024 + r1];
  }

  for (int t = 0; t < TT; t++) {
    // prefetch next step's x-gates + token two steps ahead
    int tn = (t + 2 < TT) ? tokp[t + 2] : 0;
    f16 pfa = xgtab[tok_next * 1024 + r0];
    f16 pfb = xgtab[tok_next * 1024 + r1];

    float acc0 = xga, acc1 = xgb;
#pragma unroll
    for (int m = 0; m < RK; m++) {
      unsigned int hw = (m < 64) ? h2a : h2b;
      unsigned int hs = (unsigned int)__builtin_amdgcn_readlane((int)hw, m & 63);
      f16x2 hh = __builtin_bit_cast(f16x2, hs);
      acc0 = fdot2(__builtin_bit_cast(f16x2, w0[m]), hh, acc0);
      acc1 = fdot2(__builtin_bit_cast(f16x2, w1[m]), hh, acc1);
    }
#pragma unroll
    for (int m = RK; m < 128; m++) {    // RK >= 64: always h2b here
      unsigned int hs = (unsigned int)__builtin_amdgcn_readlane((int)h2b, m & 63);
      f16x2 hh = __builtin_bit_cast(f16x2, hs);
      f16x2 wa = __builtin_bit_cast(f16x2, lw[(m - RK) * 1024 + r0]);
      f16x2 wb = __builtin_bit_cast(f16x2, lw[(m - RK) * 1024 + r1]);
      acc0 = fdot2(wa, hh, acc0);
      acc1 = fdot2(wb, hh, acc1);
    }

    if (tid >= NHID) { fo_f[tid - NHID] = acc0; fo_o[tid - NHID] = acc1; }
    __syncthreads();
    if (tid < NHID) {
      float ig = sigm(acc0);
      float gg = tanh_(acc1);
      float fg = sigm(fo_f[tid]);
      float og = sigm(fo_o[tid]);
      c = fg * c + ig * gg;
      hnew = og * tanh_(c);
      if (t < L) pool += hnew;
      hbuf[tid] = hnew;
    }
    __syncthreads();
    {
      float2 p = *(const float2*)&hbuf[2 * lane];
      float2 q = *(const float2*)&hbuf[128 + 2 * lane];
      f16x2 ph; ph[0] = (f16)p.x; ph[1] = (f16)p.y;
      f16x2 qh; qh[0] = (f16)q.x; qh[1] = (f16)q.y;
      h2a = __builtin_bit_cast(unsigned int, ph);
      h2b = __builtin_bit_cast(unsigned int, qh);
    }
    xga = (float)pfa; xgb = (float)pfb; tok_next = tn;
  }

  if (tid < NHID) {
    feat[b * NHID + tid] = pool / (float)L;
    out_hx[b * NHID + tid] = hnew;
    out_cx[b * NHID + tid] = c;
  }
}

// ------------------------------------------------------------- k3: head (fp32)
__global__ __launch_bounds__(256) void k3_head(const float* __restrict__ feat,
    const float* __restrict__ rfc1_w, const float* __restrict__ rfc1_b,
    const float* __restrict__ rbn_g, const float* __restrict__ rbn_b,
    const float* __restrict__ rbn_rm, const float* __restrict__ rbn_rv,
    const float* __restrict__ rfc2_w, const float* __restrict__ rfc2_b,
    const float* __restrict__ fc1_w, const float* __restrict__ fc1_b,
    const float* __restrict__ bn1_g, const float* __restrict__ bn1_b,
    const float* __restrict__ bn1_rm, const float* __restrict__ bn1_rv,
    const float* __restrict__ fc2_w, const float* __restrict__ fc2_b,
    float* __restrict__ logp) {
  __shared__ float f[256];
  __shared__ float f2[256];
  __shared__ float res[16];
  __shared__ float fcv[96];
  const int b = blockIdx.x, tid = threadIdx.x;
  const int wv = tid >> 6, lane = tid & 63;
  f[tid] = feat[b * 256 + tid];
  __syncthreads();
  // res = bn(relu(relu(f) @ rfc1_w.T + rfc1_b))
  for (int r = wv; r < NRES; r += 4) {
    float p = 0.f;
#pragma unroll
    for (int j0 = 0; j0 < 4; j0++) {
      int j = lane * 4 + j0;
      p += fmaxf(f[j], 0.f) * rfc1_w[r * 256 + j];
    }
    for (int off = 32; off > 0; off >>= 1) p += __shfl_down(p, off);
    if (lane == 0) {
      float x = p + rfc1_b[r];
      x = fmaxf(x, 0.f);
      x = (x - rbn_rm[r]) * rsqrtf(rbn_rv[r] + EPSV) * rbn_g[r] + rbn_b[r];
      res[r] = x;
    }
  }
  __syncthreads();
  {
    float s = rfc2_b[tid];
#pragma unroll
    for (int r = 0; r < NRES; r++) s += res[r] * rfc2_w[tid * NRES + r];
    f2[tid] = f[tid] + s;
  }
  __syncthreads();
  // fc = lrelu(bn(f2 @ fc1_w.T + fc1_b))
  for (int o = wv; o < NFC1; o += 4) {
    float p = 0.f;
#pragma unroll
    for (int j0 = 0; j0 < 4; j0++) {
      int j = lane * 4 + j0;
      p += f2[j] * fc1_w[o * 256 + j];
    }
    for (int off = 32; off > 0; off >>= 1) p += __shfl_down(p, off);
    if (lane == 0) {
      float x = p + fc1_b[o];
      x = (x - bn1_rm[o]) * rsqrtf(bn1_rv[o] + EPSV) * bn1_g[o] + bn1_b[o];
      x = fmaxf(x, 0.01f * x);   // lrelu
      fcv[o] = x;
    }
  }
  __syncthreads();
  if (tid == 0) {
    float l0 = fc2_b[0], l1 = fc2_b[1];
    for (int o2 = 0; o2 < NFC1; o2++) {
      l0 += fcv[o2] * fc2_w[o2];
      l1 += fcv[o2] * fc2_w[NFC1 + o2];
    }
    float mx = fmaxf(l0, l1);
    float lse = mx + __logf(__expf(l0 - mx) + __expf(l1 - mx));
    logp[b * 2 + 0] = l0 - lse;
    logp[b * 2 + 1] = l1 - lse;
  }
}

// ---------------------------------------------------------------------------
extern "C" void kernel_launch(void* const* d_in, const int* in_sizes, int n_in,
                              void* d_out, int out_size, void* d_ws, size_t ws_size,
                              hipStream_t stream) {
  const int*   input  = (const int*)  d_in[0];
  const float* hx     = (const float*)d_in[1];
  const float* cx     = (const float*)d_in[2];
  const int*   seqlen = (const int*)  d_in[3];
  const float* emb_w  = (const float*)d_in[4];
  const float* W_ih   = (const float*)d_in[5];
  const float* W_hh   = (const float*)d_in[6];
  const float* b_ih   = (const float*)d_in[7];
  const float* b_hh   = (const float*)d_in[8];
  const float* rfc1_w = (const float*)d_in[9];
  const float* rfc1_b = (const float*)d_in[10];
  const float* rbn_g  = (const float*)d_in[11];
  const float* rbn_b  = (const float*)d_in[12];
  const float* rbn_rm = (const float*)d_in[13];
  const float* rbn_rv = (const float*)d_in[14];
  const float* rfc2_w = (const float*)d_in[15];
  const float* rfc2_b = (const float*)d_in[16];
  const float* fc1_w  = (const float*)d_in[17];
  const float* fc1_b  = (const float*)d_in[18];
  const float* bn1_g  = (const float*)d_in[19];
  const float* bn1_b  = (const float*)d_in[20];
  const float* bn1_rm = (const float*)d_in[21];
  const float* bn1_rv = (const float*)d_in[22];
  const float* fc2_w  = (const float*)d_in[23];
  const float* fc2_b  = (const float*)d_in[24];

  // workspace layout (bytes); total ~129.3 MB
  char* ws = (char*)d_ws;
  f16*   emb16 = (f16*)(ws);                 // 50257*256*2 = 25,731,584
  f16*   wih16 = (f16*)(ws + 25731584);      // 1024*256*2  =    524,288
  float* bias  = (float*)(ws + 26255872);    // 1024*4      =      4,096
  f16*   xgtab = (f16*)(ws + 26259968);      // 50257*1024*2= 102,926,336
  float* feat  = (float*)(ws + 129186304);   // 64*256*4    =     65,536

  float* out = (float*)d_out;   // [0,128): logp, [128,16512): hx_f, [16512,32896): cx_f

  k0_convert<<<dim3(NTOKEN), 256, 0, stream>>>(emb_w, W_ih, b_ih, b_hh, emb16, wih16, bias);
  k1_gemm<<<dim3((NTOKEN + 63) / 64, 4), 256, 0, stream>>>(emb16, wih16, bias, xgtab);
  k2_rnn<<<dim3(BB), 512, 0, stream>>>(input, hx, cx, seqlen, W_hh, xgtab, feat,
                                       out + 128, out + 128 + BB * NHID);
  k3_head<<<dim3(BB), 256, 0, stream>>>(feat, rfc1_w, rfc1_b, rbn_g, rbn_b, rbn_rm, rbn_rv,
                                        rfc2_w, rfc2_b, fc1_w, fc1_b, bn1_g, bn1_b, bn1_rm,
                                        bn1_rv, fc2_w, fc2_b, out);
}

// Round 2
// 4164.846 us; speedup vs baseline: 1.2082x; 1.2082x over previous
//
#include <hip/hip_runtime.h>
#include <cstdint>

// ---------------------------------------------------------------------------
// RNNres: emb -> LSTM(T=2048,B=64,NHID=256) -> ragged mean pool -> ResNet head
//   k0: convert emb_w / W_ih to f16, bias = b_ih + b_hh
//   k1: MFMA f16 GEMM: gate_table[v] = W_ih * emb_w[v] + bias   (50257 x 1024)
//   k2: persistent recurrence, 1 WG/batch. h broadcast via same-address
//       ds_read_b128 (LDS broadcast, no readlane). W_hh: 92/128 half2 pairs
//       per row in VGPRs, 36/128 in LDS as adjacent uint2 (b64 reads).
//   k3: tiny fp32 head
// ---------------------------------------------------------------------------

#define NTOKEN 50257
#define NINP 256
#define NHID 256
#define BB 64
#define TT 2048
#define NRES 10
#define NFC1 85
#define EPSV 1e-5f

typedef _Float16 f16;
typedef _Float16 f16x2 __attribute__((ext_vector_type(2)));
typedef _Float16 f16x8 __attribute__((ext_vector_type(8)));
typedef float f32x4 __attribute__((ext_vector_type(4)));

static __device__ __forceinline__ float sigm(float x) { return 1.0f / (1.0f + __expf(-x)); }
static __device__ __forceinline__ float tanh_(float x) {
  float ax = fabsf(x);
  float e = __expf(-2.0f * ax);
  float t = (1.0f - e) / (1.0f + e);
  return x < 0.0f ? -t : t;
}

static __device__ __forceinline__ float fdot2(f16x2 a, f16x2 b, float c) {
#if __has_builtin(__builtin_amdgcn_fdot2)
  return __builtin_amdgcn_fdot2(a, b, c, false);
#else
  return c + (float)a[0] * (float)b[0] + (float)a[1] * (float)b[1];
#endif
}

// ---------------------------------------------------------------- k0: convert
__global__ void k0_convert(const float* __restrict__ emb_w, const float* __restrict__ W_ih,
                           const float* __restrict__ b_ih, const float* __restrict__ b_hh,
                           f16* __restrict__ emb16, f16* __restrict__ wih16,
                           float* __restrict__ bias) {
  int64_t i = (int64_t)blockIdx.x * blockDim.x + threadIdx.x;
  if (i < (int64_t)NTOKEN * NINP) emb16[i] = (f16)emb_w[i];
  if (i < 4 * NHID * NINP) wih16[i] = (f16)W_ih[i];
  if (i < 4 * NHID) bias[i] = b_ih[i] + b_hh[i];
}

// ------------------------------------------------- k1: gate-table f16 GEMM
__global__ __launch_bounds__(256) void k1_gemm(const f16* __restrict__ emb16,
                                               const f16* __restrict__ wih16,
                                               const float* __restrict__ bias,
                                               f16* __restrict__ xgtab) {
  __shared__ __align__(16) f16 a_lds[64][40];
  __shared__ __align__(16) f16 b_lds[256][40];
  const int mt = blockIdx.x;
  const int nt0 = blockIdx.y * 256;
  const int tid = threadIdx.x;
  const int lane = tid & 63;
  const int w = tid >> 6;
  const int quad = lane >> 4;
  const int l16 = lane & 15;

  f32x4 acc[16];
#pragma unroll
  for (int i = 0; i < 16; i++) acc[i] = (f32x4){0.f, 0.f, 0.f, 0.f};

  const int ar = tid >> 2;
  int av = mt * 64 + ar;
  if (av > NTOKEN - 1) av = NTOKEN - 1;
  const int ac = (tid & 3) * 8;

  for (int kb = 0; kb < 256; kb += 32) {
    *(uint4*)&a_lds[ar][ac] = *(const uint4*)&emb16[av * 256 + kb + ac];
    {
      const uint4* bs = (const uint4*)&wih16[(nt0 + tid) * 256 + kb];
      uint4* bd = (uint4*)&b_lds[tid][0];
      bd[0] = bs[0]; bd[1] = bs[1]; bd[2] = bs[2]; bd[3] = bs[3];
    }
    __syncthreads();
    f16x8 af = *(const f16x8*)&a_lds[w * 16 + l16][quad * 8];
#pragma unroll
    for (int nt = 0; nt < 16; nt++) {
      f16x8 bf = *(const f16x8*)&b_lds[nt * 16 + l16][quad * 8];
      acc[nt] = __builtin_amdgcn_mfma_f32_16x16x32_f16(af, bf, acc[nt], 0, 0, 0);
    }
    __syncthreads();
  }
#pragma unroll
  for (int nt = 0; nt < 16; nt++) {
#pragma unroll
    for (int rg = 0; rg < 4; rg++) {
      int v = mt * 64 + w * 16 + quad * 4 + rg;
      if (v < NTOKEN) {
        int n = nt0 + nt * 16 + l16;
        xgtab[v * 1024 + n] = (f16)(acc[nt][rg] + bias[n]);
      }
    }
  }
}

// ------------------------------------------------------- k2: LSTM recurrence
// One WG per batch element, 512 thr. Thread t owns gate rows t and t+512
// (t<256: i,g ; t>=256: f,o). h kept as packed f16[256] in LDS, fetched via
// same-address ds_read_b128 broadcast (16B = 4 half2 pairs / read).
// W_hh half2 pairs: m<RK in VGPRs, m>=RK in LDS as uint2{w_r0,w_r1} (b64).
#define RK 92
#define LK 36
__global__ __launch_bounds__(512, 2) void k2_rnn(
    const int* __restrict__ input, const float* __restrict__ hx0,
    const float* __restrict__ cx0, const int* __restrict__ seq_len,
    const float* __restrict__ Whh, const f16* __restrict__ xgtab,
    float* __restrict__ feat, float* __restrict__ out_hx, float* __restrict__ out_cx) {
  __shared__ uint2 lw2[LK * 512];                 // 147456 B
  __shared__ __align__(16) f16 hpak[NHID];        // 512 B
  __shared__ float fo_f[NHID];
  __shared__ float fo_o[NHID];

  const int b = blockIdx.x;
  const int tid = threadIdx.x;
  const int r0 = tid, r1 = tid + 512;

  // ---- load + pack W_hh (fp32 -> half2), split regs/LDS
  unsigned int w0[RK], w1[RK];
#pragma unroll
  for (int m = 0; m < 128; m++) {
    float2 a = *(const float2*)&Whh[r0 * 256 + 2 * m];
    float2 d = *(const float2*)&Whh[r1 * 256 + 2 * m];
    f16x2 pa; pa[0] = (f16)a.x; pa[1] = (f16)a.y;
    f16x2 pd; pd[0] = (f16)d.x; pd[1] = (f16)d.y;
    unsigned int ua = __builtin_bit_cast(unsigned int, pa);
    unsigned int ud = __builtin_bit_cast(unsigned int, pd);
    if (m < RK) { w0[m] = ua; w1[m] = ud; }
    else { lw2[(m - RK) * 512 + tid] = make_uint2(ua, ud); }
  }

  float c = 0.0f, pool = 0.0f, hnew = 0.0f;
  if (tid < NHID) {
    hpak[tid] = (f16)hx0[b * NHID + tid];
    c = cx0[b * NHID + tid];
  }
  const int L = seq_len[b];
  __syncthreads();

  const int* tokp = input + b * TT;
  int tok_next = tokp[1];
  f16 xga, xgb;
  {
    int tok0 = tokp[0];
    xga = xgtab[tok0 * 1024 + r0];
    xgb = xgtab[tok0 * 1024 + r1];
  }

  for (int t = 0; t < TT; t++) {
    int tn = (t + 2 < TT) ? tokp[t + 2] : 0;
    f16 pfa = xgtab[tok_next * 1024 + r0];
    f16 pfb = xgtab[tok_next * 1024 + r1];

    float acc0 = (float)xga, acc1 = (float)xgb;
    const uint4* hp = (const uint4*)hpak;
#pragma unroll
    for (int mb = 0; mb < 32; mb++) {
      uint4 h4 = hp[mb];  // ds_read_b128, same address across wave -> broadcast
#pragma unroll
      for (int j = 0; j < 4; j++) {
        const int m = mb * 4 + j;
        unsigned int hu = (j == 0) ? h4.x : (j == 1) ? h4.y : (j == 2) ? h4.z : h4.w;
        f16x2 hh = __builtin_bit_cast(f16x2, hu);
        f16x2 wa, wb;
        if (m < RK) {
          wa = __builtin_bit_cast(f16x2, w0[m]);
          wb = __builtin_bit_cast(f16x2, w1[m]);
        } else {
          uint2 ww = lw2[(m - RK) * 512 + tid];   // ds_read_b64, stride-1
          wa = __builtin_bit_cast(f16x2, ww.x);
          wb = __builtin_bit_cast(f16x2, ww.y);
        }
        acc0 = fdot2(wa, hh, acc0);
        acc1 = fdot2(wb, hh, acc1);
      }
    }

    // f,o gates: sigmoid on the upper waves (spreads transcendental work)
    if (tid >= NHID) {
      fo_f[tid - NHID] = sigm(acc0);
      fo_o[tid - NHID] = sigm(acc1);
    }
    __syncthreads();
    if (tid < NHID) {
      float ig = sigm(acc0);
      float gg = tanh_(acc1);
      c = fo_f[tid] * c + ig * gg;
      hnew = fo_o[tid] * tanh_(c);
      if (t < L) pool += hnew;
      hpak[tid] = (f16)hnew;
    }
    __syncthreads();
    xga = pfa; xgb = pfb; tok_next = tn;
  }

  if (tid < NHID) {
    feat[b * NHID + tid] = pool / (float)L;
    out_hx[b * NHID + tid] = hnew;
    out_cx[b * NHID + tid] = c;
  }
}

// ------------------------------------------------------------- k3: head (fp32)
__global__ __launch_bounds__(256) void k3_head(const float* __restrict__ feat,
    const float* __restrict__ rfc1_w, const float* __restrict__ rfc1_b,
    const float* __restrict__ rbn_g, const float* __restrict__ rbn_b,
    const float* __restrict__ rbn_rm, const float* __restrict__ rbn_rv,
    const float* __restrict__ rfc2_w, const float* __restrict__ rfc2_b,
    const float* __restrict__ fc1_w, const float* __restrict__ fc1_b,
    const float* __restrict__ bn1_g, const float* __restrict__ bn1_b,
    const float* __restrict__ bn1_rm, const float* __restrict__ bn1_rv,
    const float* __restrict__ fc2_w, const float* __restrict__ fc2_b,
    float* __restrict__ logp) {
  __shared__ float f[256];
  __shared__ float f2[256];
  __shared__ float res[16];
  __shared__ float fcv[96];
  const int b = blockIdx.x, tid = threadIdx.x;
  const int wv = tid >> 6, lane = tid & 63;
  f[tid] = feat[b * 256 + tid];
  __syncthreads();
  for (int r = wv; r < NRES; r += 4) {
    float p = 0.f;
#pragma unroll
    for (int j0 = 0; j0 < 4; j0++) {
      int j = lane * 4 + j0;
      p += fmaxf(f[j], 0.f) * rfc1_w[r * 256 + j];
    }
    for (int off = 32; off > 0; off >>= 1) p += __shfl_down(p, off);
    if (lane == 0) {
      float x = p + rfc1_b[r];
      x = fmaxf(x, 0.f);
      x = (x - rbn_rm[r]) * rsqrtf(rbn_rv[r] + EPSV) * rbn_g[r] + rbn_b[r];
      res[r] = x;
    }
  }
  __syncthreads();
  {
    float s = rfc2_b[tid];
#pragma unroll
    for (int r = 0; r < NRES; r++) s += res[r] * rfc2_w[tid * NRES + r];
    f2[tid] = f[tid] + s;
  }
  __syncthreads();
  for (int o = wv; o < NFC1; o += 4) {
    float p = 0.f;
#pragma unroll
    for (int j0 = 0; j0 < 4; j0++) {
      int j = lane * 4 + j0;
      p += f2[j] * fc1_w[o * 256 + j];
    }
    for (int off = 32; off > 0; off >>= 1) p += __shfl_down(p, off);
    if (lane == 0) {
      float x = p + fc1_b[o];
      x = (x - bn1_rm[o]) * rsqrtf(bn1_rv[o] + EPSV) * bn1_g[o] + bn1_b[o];
      x = fmaxf(x, 0.01f * x);
      fcv[o] = x;
    }
  }
  __syncthreads();
  if (tid == 0) {
    float l0 = fc2_b[0], l1 = fc2_b[1];
    for (int o2 = 0; o2 < NFC1; o2++) {
      l0 += fcv[o2] * fc2_w[o2];
      l1 += fcv[o2] * fc2_w[NFC1 + o2];
    }
    float mx = fmaxf(l0, l1);
    float lse = mx + __logf(__expf(l0 - mx) + __expf(l1 - mx));
    logp[b * 2 + 0] = l0 - lse;
    logp[b * 2 + 1] = l1 - lse;
  }
}

// ---------------------------------------------------------------------------
extern "C" void kernel_launch(void* const* d_in, const int* in_sizes, int n_in,
                              void* d_out, int out_size, void* d_ws, size_t ws_size,
                              hipStream_t stream) {
  const int*   input  = (const int*)  d_in[0];
  const float* hx     = (const float*)d_in[1];
  const float* cx     = (const float*)d_in[2];
  const int*   seqlen = (const int*)  d_in[3];
  const float* emb_w  = (const float*)d_in[4];
  const float* W_ih   = (const float*)d_in[5];
  const float* W_hh   = (const float*)d_in[6];
  const float* b_ih   = (const float*)d_in[7];
  const float* b_hh   = (const float*)d_in[8];
  const float* rfc1_w = (const float*)d_in[9];
  const float* rfc1_b = (const float*)d_in[10];
  const float* rbn_g  = (const float*)d_in[11];
  const float* rbn_b  = (const float*)d_in[12];
  const float* rbn_rm = (const float*)d_in[13];
  const float* rbn_rv = (const float*)d_in[14];
  const float* rfc2_w = (const float*)d_in[15];
  const float* rfc2_b = (const float*)d_in[16];
  const float* fc1_w  = (const float*)d_in[17];
  const float* fc1_b  = (const float*)d_in[18];
  const float* bn1_g  = (const float*)d_in[19];
  const float* bn1_b  = (const float*)d_in[20];
  const float* bn1_rm = (const float*)d_in[21];
  const float* bn1_rv = (const float*)d_in[22];
  const float* fc2_w  = (const float*)d_in[23];
  const float* fc2_b  = (const float*)d_in[24];

  char* ws = (char*)d_ws;
  f16*   emb16 = (f16*)(ws);                 // 25,731,584 B
  f16*   wih16 = (f16*)(ws + 25731584);      //    524,288 B
  float* bias  = (float*)(ws + 26255872);    //      4,096 B
  f16*   xgtab = (f16*)(ws + 26259968);      // 102,926,336 B
  float* feat  = (float*)(ws + 129186304);   //     65,536 B

  float* out = (float*)d_out;   // [0,128): logp, [128,16512): hx_f, [16512,32896): cx_f

  k0_convert<<<dim3(NTOKEN), 256, 0, stream>>>(emb_w, W_ih, b_ih, b_hh, emb16, wih16, bias);
  k1_gemm<<<dim3((NTOKEN + 63) / 64, 4), 256, 0, stream>>>(emb16, wih16, bias, xgtab);
  k2_rnn<<<dim3(BB), 512, 0, stream>>>(input, hx, cx, seqlen, W_hh, xgtab, feat,
                                       out + 128, out + 128 + BB * NHID);
  k3_head<<<dim3(BB), 256, 0, stream>>>(feat, rfc1_w, rfc1_b, rbn_g, rbn_b, rbn_rm, rbn_rv,
                                        rfc2_w, rfc2_b, fc1_w, fc1_b, bn1_g, bn1_b, bn1_rm,
                                        bn1_rv, fc2_w, fc2_b, out);
}